// Round 1
// baseline (7431.147 us; speedup 1.0000x reference)
//
#include <hip/hip_runtime.h>

#define DD 64

// ---------- helpers ----------
__device__ __forceinline__ unsigned enc_f32(float x) {
  unsigned u = __float_as_uint(x);
  return (u & 0x80000000u) ? ~u : (u | 0x80000000u);
}
__device__ __forceinline__ float dec_f32(unsigned k) {
  return (k & 0x80000000u) ? __uint_as_float(k ^ 0x80000000u)
                           : __uint_as_float(~k);
}

// ---------- dense: hr[n,r,:] = h@Wrel[r], hnext = h@Wloop + brel ----------
// one lane per node (64 nodes/block row-group), one wave per 16-col chunk.
// Weights read via wave-uniform (scalar) loads.
__global__ __launch_bounds__(256) void rgcn_dense(
    const float* __restrict__ hin, const float* __restrict__ Wrel,
    const float* __restrict__ Wloop, const float* __restrict__ brel,
    float* __restrict__ hr, float* __restrict__ hnext, int N, int relu_in) {
  const int lane = threadIdx.x & 63;
  const int wv = threadIdx.x >> 6;                       // 0..3
  const int c0 = __builtin_amdgcn_readfirstlane(wv << 4);  // uniform col chunk
  const int n = blockIdx.x * 64 + lane;

  float h[DD];
  if (n < N) {
    const float4* hp = (const float4*)(hin + (size_t)n * DD);
#pragma unroll
    for (int t = 0; t < DD / 4; ++t) {
      float4 v = hp[t];
      if (relu_in) {
        v.x = fmaxf(v.x, 0.f); v.y = fmaxf(v.y, 0.f);
        v.z = fmaxf(v.z, 0.f); v.w = fmaxf(v.w, 0.f);
      }
      h[4 * t + 0] = v.x; h[4 * t + 1] = v.y;
      h[4 * t + 2] = v.z; h[4 * t + 3] = v.w;
    }
  } else {
#pragma unroll
    for (int t = 0; t < DD; ++t) h[t] = 0.f;
  }

#pragma unroll 1
  for (int m = 0; m < 5; ++m) {
    const float* __restrict__ W =
        (m < 4) ? (Wrel + (size_t)m * DD * DD) : Wloop;
    float acc[16];
#pragma unroll
    for (int j = 0; j < 16; ++j) acc[j] = 0.f;
#pragma unroll
    for (int k = 0; k < DD; ++k) {
      const float hk = h[k];
#pragma unroll
      for (int j = 0; j < 16; ++j)
        acc[j] = fmaf(hk, W[k * DD + c0 + j], acc[j]);
    }
    if (n < N) {
      if (m < 4) {
        float* o = hr + (((size_t)n * 4 + m) << 6) + c0;
#pragma unroll
        for (int j = 0; j < 16; j += 4)
          *(float4*)(o + j) =
              make_float4(acc[j], acc[j + 1], acc[j + 2], acc[j + 3]);
      } else {
        float* o = hnext + ((size_t)n << 6) + c0;
#pragma unroll
        for (int j = 0; j < 16; j += 4)
          *(float4*)(o + j) = make_float4(
              acc[j] + brel[c0 + j], acc[j + 1] + brel[c0 + j + 1],
              acc[j + 2] + brel[c0 + j + 2], acc[j + 3] + brel[c0 + j + 3]);
      }
    }
  }
}

// ---------- z = relu(h) @ W (single 64x64 matrix) ----------
__global__ __launch_bounds__(256) void gemm_relu64(
    const float* __restrict__ hin, const float* __restrict__ W,
    float* __restrict__ out, int N) {
  const int lane = threadIdx.x & 63;
  const int wv = threadIdx.x >> 6;
  const int c0 = __builtin_amdgcn_readfirstlane(wv << 4);
  const int n = blockIdx.x * 64 + lane;

  float h[DD];
  if (n < N) {
    const float4* hp = (const float4*)(hin + (size_t)n * DD);
#pragma unroll
    for (int t = 0; t < DD / 4; ++t) {
      float4 v = hp[t];
      v.x = fmaxf(v.x, 0.f); v.y = fmaxf(v.y, 0.f);
      v.z = fmaxf(v.z, 0.f); v.w = fmaxf(v.w, 0.f);
      h[4 * t + 0] = v.x; h[4 * t + 1] = v.y;
      h[4 * t + 2] = v.z; h[4 * t + 3] = v.w;
    }
  } else {
#pragma unroll
    for (int t = 0; t < DD; ++t) h[t] = 0.f;
  }
  float acc[16];
#pragma unroll
  for (int j = 0; j < 16; ++j) acc[j] = 0.f;
#pragma unroll
  for (int k = 0; k < DD; ++k) {
    const float hk = h[k];
#pragma unroll
    for (int j = 0; j < 16; ++j)
      acc[j] = fmaf(hk, W[k * DD + c0 + j], acc[j]);
  }
  if (n < N) {
    float* o = out + ((size_t)n << 6) + c0;
#pragma unroll
    for (int j = 0; j < 16; j += 4)
      *(float4*)(o + j) =
          make_float4(acc[j], acc[j + 1], acc[j + 2], acc[j + 3]);
  }
}

// ---------- edge scatter: hnext[dst] += hr[src, etype] ----------
__global__ __launch_bounds__(256) void scatter_rgcn(
    const float* __restrict__ hr, const int* __restrict__ src,
    const int* __restrict__ dst, const int* __restrict__ et,
    float* __restrict__ hnext, int E) {
  int tid = blockIdx.x * 256 + threadIdx.x;
  int e = tid >> 4, q = tid & 15;
  if (e >= E) return;
  int s = src[e], d = dst[e], t = et[e];
  float4 v = *(const float4*)(hr + (((size_t)s * 4 + t) << 6) + q * 4);
  float* o = hnext + ((size_t)d << 6) + q * 4;
  unsafeAtomicAdd(o + 0, v.x);
  unsafeAtomicAdd(o + 1, v.y);
  unsafeAtomicAdd(o + 2, v.z);
  unsafeAtomicAdd(o + 3, v.w);
}

// ---------- GAT: el/er per node ----------
__global__ __launch_bounds__(256) void el_er_k(
    const float* __restrict__ z, const float* __restrict__ al,
    const float* __restrict__ ar, float* __restrict__ el,
    float* __restrict__ er, int N) {
  int n = blockIdx.x * 4 + (threadIdx.x >> 6);
  int lane = threadIdx.x & 63;
  if (n >= N) return;
  float v = z[(size_t)n * DD + lane];
  float pl = v * al[lane];
  float pr = v * ar[lane];
#pragma unroll
  for (int off = 32; off > 0; off >>= 1) {
    pl += __shfl_down(pl, off);
    pr += __shfl_down(pr, off);
  }
  if (lane == 0) { el[n] = pl; er[n] = pr; }
}

// ---------- GAT pass 1: e = leaky(el[s]+er[d]); segment max ----------
__global__ __launch_bounds__(256) void gat_e1(
    const float* __restrict__ el, const float* __restrict__ er,
    const int* __restrict__ src, const int* __restrict__ dst,
    float* __restrict__ eE, unsigned* __restrict__ menc, int E) {
  int e = blockIdx.x * 256 + threadIdx.x;
  if (e >= E) return;
  float x = el[src[e]] + er[dst[e]];
  x = (x > 0.f) ? x : 0.2f * x;
  eE[e] = x;
  atomicMax(menc + dst[e], enc_f32(x));
}

// ---------- GAT pass 2: ex = exp(e - m[d]); den += ex ----------
__global__ __launch_bounds__(256) void gat_e2(
    const float* __restrict__ eE, const unsigned* __restrict__ menc,
    const int* __restrict__ dst, float* __restrict__ exE,
    float* __restrict__ den, int E) {
  int e = blockIdx.x * 256 + threadIdx.x;
  if (e >= E) return;
  int d = dst[e];
  float ex = __expf(eE[e] - dec_f32(menc[d]));
  exE[e] = ex;
  unsafeAtomicAdd(den + d, ex);
}

// ---------- GAT pass 3: hg[d] += alpha * z[s] ----------
__global__ __launch_bounds__(256) void gat_scatter(
    const float* __restrict__ z, const float* __restrict__ exE,
    const float* __restrict__ den, const int* __restrict__ src,
    const int* __restrict__ dst, float* __restrict__ hg, int E) {
  int tid = blockIdx.x * 256 + threadIdx.x;
  int e = tid >> 4, q = tid & 15;
  if (e >= E) return;
  int s = src[e], d = dst[e];
  float w = exE[e] / fmaxf(den[d], 1e-9f);
  float4 v = *(const float4*)(z + ((size_t)s << 6) + q * 4);
  float* o = hg + ((size_t)d << 6) + q * 4;
  unsafeAtomicAdd(o + 0, w * v.x);
  unsafeAtomicAdd(o + 1, w * v.y);
  unsafeAtomicAdd(o + 2, w * v.z);
  unsafeAtomicAdd(o + 3, w * v.w);
}

// ---------- pooled head: out[g] += dot(hg[n], Wd) ----------
__global__ __launch_bounds__(256) void pool_head(
    const float* __restrict__ hg, const float* __restrict__ Wd,
    const int* __restrict__ gids, float* __restrict__ out, int N) {
  int n = blockIdx.x * 4 + (threadIdx.x >> 6);
  int lane = threadIdx.x & 63;
  if (n >= N) return;
  float v = hg[(size_t)n * DD + lane] * Wd[lane];
#pragma unroll
  for (int off = 32; off > 0; off >>= 1) v += __shfl_down(v, off);
  if (lane == 0) unsafeAtomicAdd(out + gids[n], v);
}

__global__ void init_out_k(float* out, const float* bd, int n) {
  int i = blockIdx.x * blockDim.x + threadIdx.x;
  if (i < n) out[i] = bd[0];
}

// ---------- launch ----------
extern "C" void kernel_launch(void* const* d_in, const int* in_sizes, int n_in,
                              void* d_out, int out_size, void* d_ws,
                              size_t ws_size, hipStream_t stream) {
  const float* h0 = (const float*)d_in[0];
  const float* Wrel = (const float*)d_in[1];
  const float* Wloop = (const float*)d_in[2];
  const float* brel = (const float*)d_in[3];
  const float* Wg = (const float*)d_in[4];
  const float* al = (const float*)d_in[5];
  const float* ar = (const float*)d_in[6];
  const float* Wd = (const float*)d_in[7];
  const float* bd = (const float*)d_in[8];
  const int* src = (const int*)d_in[9];
  const int* dst = (const int*)d_in[10];
  const int* et = (const int*)d_in[11];
  const int* gids = (const int*)d_in[12];

  const int N = in_sizes[0] / DD;
  const int E = in_sizes[9];
  const int L = in_sizes[2] / (DD * DD);
  const int R = in_sizes[1] / (L * DD * DD);  // == 4
  (void)R;
  float* out = (float*)d_out;

  float* wsf = (float*)d_ws;
  float* hA = wsf;
  float* hB = hA + (size_t)N * DD;
  float* hr = hB + (size_t)N * DD;  // N*4*DD floats
  // GAT overlays in the hr region (used only after the RGCN layers):
  float* hg = hr;                       // N*DD
  float* eE = hr + (size_t)N * DD;      // E
  float* exE = eE + E;                  // E
  float* el = exE + E;                  // N
  float* er = el + N;                   // N
  unsigned* menc = (unsigned*)(er + N); // N
  float* den = (float*)(menc + N);      // N

  dim3 b256(256);
  const int grid_dense = (N + 63) / 64;
  const int grid_sc = (int)(((size_t)E * 16 + 255) / 256);
  const int grid_e = (E + 255) / 256;
  const int grid_n4 = (N + 3) / 4;

  hipLaunchKernelGGL(init_out_k, dim3((out_size + 255) / 256), b256, 0, stream,
                     out, bd, out_size);

  const float* cur = h0;
  float* nxt = hA;
  for (int l = 0; l < L; ++l) {
    hipLaunchKernelGGL(rgcn_dense, dim3(grid_dense), b256, 0, stream, cur,
                       Wrel + (size_t)l * 4 * DD * DD,
                       Wloop + (size_t)l * DD * DD, brel + (size_t)l * DD, hr,
                       nxt, N, l > 0 ? 1 : 0);
    hipLaunchKernelGGL(scatter_rgcn, dim3(grid_sc), b256, 0, stream, hr, src,
                       dst, et, nxt, E);
    cur = nxt;
    nxt = (cur == hA) ? hB : hA;
  }
  // cur = final (pre-relu) h; nxt = free buffer -> use for z
  float* zb = nxt;

  hipMemsetAsync(menc, 0, (size_t)N * 4, stream);
  hipMemsetAsync(den, 0, (size_t)N * 4, stream);
  hipMemsetAsync(hg, 0, (size_t)N * DD * 4, stream);

  hipLaunchKernelGGL(gemm_relu64, dim3(grid_dense), b256, 0, stream, cur, Wg,
                     zb, N);
  hipLaunchKernelGGL(el_er_k, dim3(grid_n4), b256, 0, stream, zb, al, ar, el,
                     er, N);
  hipLaunchKernelGGL(gat_e1, dim3(grid_e), b256, 0, stream, el, er, src, dst,
                     eE, menc, E);
  hipLaunchKernelGGL(gat_e2, dim3(grid_e), b256, 0, stream, eE, menc, dst, exE,
                     den, E);
  hipLaunchKernelGGL(gat_scatter, dim3(grid_sc), b256, 0, stream, zb, exE, den,
                     src, dst, hg, E);
  hipLaunchKernelGGL(pool_head, dim3(grid_n4), b256, 0, stream, hg, Wd, gids,
                     out, N);
}

// Round 2
// 1393.594 us; speedup vs baseline: 5.3324x; 5.3324x over previous
//
#include <hip/hip_runtime.h>

#define DD 64

// ================= CSR build =================
__global__ __launch_bounds__(256) void k_deg(const int* __restrict__ dst,
                                             int* __restrict__ deg, int E) {
  int e = blockIdx.x * 256 + threadIdx.x;
  if (e < E) atomicAdd(&deg[dst[e]], 1);
}

__global__ __launch_bounds__(1024) void k_scan(const int* __restrict__ deg,
                                               int* __restrict__ rowptr,
                                               int* __restrict__ cursor, int N,
                                               int E) {
  __shared__ int part[1024];
  const int t = threadIdx.x;
  const int C = (N + 1023) / 1024;
  const int b = t * C;
  const int e = min(b + C, N);
  int s = 0;
  for (int i = b; i < e; ++i) s += deg[i];
  part[t] = s;
  __syncthreads();
  if (t == 0) {
    int run = 0;
    for (int i = 0; i < 1024; ++i) {
      int v = part[i];
      part[i] = run;
      run += v;
    }
  }
  __syncthreads();
  int run = part[t];
  for (int i = b; i < e; ++i) {
    rowptr[i] = run;
    cursor[i] = run;
    run += deg[i];
  }
  if (t == 1023) rowptr[N] = E;
}

__global__ __launch_bounds__(256) void k_fill(const int* __restrict__ src,
                                              const int* __restrict__ dst,
                                              const int* __restrict__ et,
                                              int* __restrict__ cursor,
                                              int* __restrict__ srcet, int E) {
  int e = blockIdx.x * 256 + threadIdx.x;
  if (e >= E) return;
  int pos = atomicAdd(&cursor[dst[e]], 1);
  srcet[pos] = (src[e] << 2) | et[e];
}

// ================= per-node relation gather =================
// one wave per node; lane = feature dim. aggr[n][r][d] = sum_{in-edges rel r} h[src][d]
__global__ __launch_bounds__(256) void gather_rel(
    const float* __restrict__ h, const int* __restrict__ rowptr,
    const int* __restrict__ srcet, float* __restrict__ aggr, int N,
    int relu_in) {
  const int n = blockIdx.x * 4 + (threadIdx.x >> 6);
  const int lane = threadIdx.x & 63;
  if (n >= N) return;
  const int beg = rowptr[n], end = rowptr[n + 1];
  float a0 = 0.f, a1 = 0.f, a2 = 0.f, a3 = 0.f;
  int j = beg;
  for (; j + 1 < end; j += 2) {
    const int se0 = __builtin_amdgcn_readfirstlane(srcet[j]);
    const int se1 = __builtin_amdgcn_readfirstlane(srcet[j + 1]);
    float v0 = h[((size_t)(se0 >> 2) << 6) + lane];
    float v1 = h[((size_t)(se1 >> 2) << 6) + lane];
    if (relu_in) {
      v0 = fmaxf(v0, 0.f);
      v1 = fmaxf(v1, 0.f);
    }
    const int r0 = se0 & 3, r1 = se1 & 3;
    if (r0 == 0) a0 += v0; else if (r0 == 1) a1 += v0;
    else if (r0 == 2) a2 += v0; else a3 += v0;
    if (r1 == 0) a0 += v1; else if (r1 == 1) a1 += v1;
    else if (r1 == 2) a2 += v1; else a3 += v1;
  }
  if (j < end) {
    const int se0 = __builtin_amdgcn_readfirstlane(srcet[j]);
    float v0 = h[((size_t)(se0 >> 2) << 6) + lane];
    if (relu_in) v0 = fmaxf(v0, 0.f);
    const int r0 = se0 & 3;
    if (r0 == 0) a0 += v0; else if (r0 == 1) a1 += v0;
    else if (r0 == 2) a2 += v0; else a3 += v0;
  }
  float* o = aggr + ((size_t)n << 8);
  o[lane] = a0;
  o[64 + lane] = a1;
  o[128 + lane] = a2;
  o[192 + lane] = a3;
}

// ================= dense: hnext = sum_r aggr[r]@Wrel[r] + relu?(h)@Wloop + brel ==========
__global__ __launch_bounds__(256) void rgcn_dense(
    const float* __restrict__ aggr, const float* __restrict__ hin,
    const float* __restrict__ Wrel, const float* __restrict__ Wloop,
    const float* __restrict__ brel, float* __restrict__ hnext, int N,
    int relu_in) {
  const int lane = threadIdx.x & 63;
  const int wv = threadIdx.x >> 6;
  const int c0 = __builtin_amdgcn_readfirstlane(wv << 4);
  const int n = blockIdx.x * 64 + lane;

  float acc[16];
#pragma unroll
  for (int jj = 0; jj < 16; ++jj) acc[jj] = brel[c0 + jj];

  float in[DD];
#pragma unroll 1
  for (int m = 0; m < 5; ++m) {
    const float* __restrict__ W =
        (m < 4) ? (Wrel + (size_t)m * DD * DD) : Wloop;
    if (n < N) {
      const float4* p = (m < 4)
                            ? (const float4*)(aggr + ((size_t)n << 8) + (m << 6))
                            : (const float4*)(hin + ((size_t)n << 6));
#pragma unroll
      for (int t = 0; t < DD / 4; ++t) {
        float4 v = p[t];
        if (m == 4 && relu_in) {
          v.x = fmaxf(v.x, 0.f); v.y = fmaxf(v.y, 0.f);
          v.z = fmaxf(v.z, 0.f); v.w = fmaxf(v.w, 0.f);
        }
        in[4 * t + 0] = v.x; in[4 * t + 1] = v.y;
        in[4 * t + 2] = v.z; in[4 * t + 3] = v.w;
      }
    } else {
#pragma unroll
      for (int t = 0; t < DD; ++t) in[t] = 0.f;
    }
#pragma unroll
    for (int k = 0; k < DD; ++k) {
      const float hk = in[k];
#pragma unroll
      for (int jj = 0; jj < 16; ++jj)
        acc[jj] = fmaf(hk, W[k * DD + c0 + jj], acc[jj]);
    }
  }
  if (n < N) {
    float* o = hnext + ((size_t)n << 6) + c0;
#pragma unroll
    for (int jj = 0; jj < 16; jj += 4)
      *(float4*)(o + jj) =
          make_float4(acc[jj], acc[jj + 1], acc[jj + 2], acc[jj + 3]);
  }
}

// ================= z = relu(h) @ Wg =================
__global__ __launch_bounds__(256) void gemm_relu64(const float* __restrict__ hin,
                                                   const float* __restrict__ W,
                                                   float* __restrict__ out,
                                                   int N) {
  const int lane = threadIdx.x & 63;
  const int wv = threadIdx.x >> 6;
  const int c0 = __builtin_amdgcn_readfirstlane(wv << 4);
  const int n = blockIdx.x * 64 + lane;

  float h[DD];
  if (n < N) {
    const float4* hp = (const float4*)(hin + (size_t)n * DD);
#pragma unroll
    for (int t = 0; t < DD / 4; ++t) {
      float4 v = hp[t];
      v.x = fmaxf(v.x, 0.f); v.y = fmaxf(v.y, 0.f);
      v.z = fmaxf(v.z, 0.f); v.w = fmaxf(v.w, 0.f);
      h[4 * t + 0] = v.x; h[4 * t + 1] = v.y;
      h[4 * t + 2] = v.z; h[4 * t + 3] = v.w;
    }
  } else {
#pragma unroll
    for (int t = 0; t < DD; ++t) h[t] = 0.f;
  }
  float acc[16];
#pragma unroll
  for (int j = 0; j < 16; ++j) acc[j] = 0.f;
#pragma unroll
  for (int k = 0; k < DD; ++k) {
    const float hk = h[k];
#pragma unroll
    for (int j = 0; j < 16; ++j)
      acc[j] = fmaf(hk, W[k * DD + c0 + j], acc[j]);
  }
  if (n < N) {
    float* o = out + ((size_t)n << 6) + c0;
#pragma unroll
    for (int j = 0; j < 16; j += 4)
      *(float4*)(o + j) =
          make_float4(acc[j], acc[j + 1], acc[j + 2], acc[j + 3]);
  }
}

// ================= GAT: el/er per node =================
__global__ __launch_bounds__(256) void el_er_k(
    const float* __restrict__ z, const float* __restrict__ al,
    const float* __restrict__ ar, float* __restrict__ el,
    float* __restrict__ er, int N) {
  int n = blockIdx.x * 4 + (threadIdx.x >> 6);
  int lane = threadIdx.x & 63;
  if (n >= N) return;
  float v = z[(size_t)n * DD + lane];
  float pl = v * al[lane];
  float pr = v * ar[lane];
#pragma unroll
  for (int off = 32; off > 0; off >>= 1) {
    pl += __shfl_down(pl, off);
    pr += __shfl_down(pr, off);
  }
  if (lane == 0) {
    el[n] = pl;
    er[n] = pr;
  }
}

// ================= fused GAT aggregation (per destination node) =================
__global__ __launch_bounds__(256) void gat_fused(
    const float* __restrict__ z, const float* __restrict__ el,
    const float* __restrict__ er, const int* __restrict__ rowptr,
    const int* __restrict__ srcet, float* __restrict__ hg, int N) {
  const int n = blockIdx.x * 4 + (threadIdx.x >> 6);
  const int lane = threadIdx.x & 63;
  if (n >= N) return;
  const int beg = rowptr[n], end = rowptr[n + 1];
  const float ern = er[n];
  float m = -1e30f;
  for (int j = beg; j < end; ++j) {
    const int s = __builtin_amdgcn_readfirstlane(srcet[j]) >> 2;
    float x = el[s] + ern;
    x = (x > 0.f) ? x : 0.2f * x;
    m = fmaxf(m, x);
  }
  float num = 0.f, den = 0.f;
  for (int j = beg; j < end; ++j) {
    const int s = __builtin_amdgcn_readfirstlane(srcet[j]) >> 2;
    float x = el[s] + ern;
    x = (x > 0.f) ? x : 0.2f * x;
    const float w = __expf(x - m);
    den += w;
    num = fmaf(w, z[((size_t)s << 6) + lane], num);
  }
  hg[((size_t)n << 6) + lane] = num / fmaxf(den, 1e-9f);
}

// ================= pooled head =================
__global__ __launch_bounds__(256) void pool_head(
    const float* __restrict__ hg, const float* __restrict__ Wd,
    const int* __restrict__ gids, float* __restrict__ out, int N) {
  int n = blockIdx.x * 4 + (threadIdx.x >> 6);
  int lane = threadIdx.x & 63;
  if (n >= N) return;
  float v = hg[(size_t)n * DD + lane] * Wd[lane];
#pragma unroll
  for (int off = 32; off > 0; off >>= 1) v += __shfl_down(v, off);
  if (lane == 0) unsafeAtomicAdd(out + gids[n], v);
}

__global__ void init_out_k(float* out, const float* bd, int n) {
  int i = blockIdx.x * blockDim.x + threadIdx.x;
  if (i < n) out[i] = bd[0];
}

// ================= launch =================
extern "C" void kernel_launch(void* const* d_in, const int* in_sizes, int n_in,
                              void* d_out, int out_size, void* d_ws,
                              size_t ws_size, hipStream_t stream) {
  const float* h0 = (const float*)d_in[0];
  const float* Wrel = (const float*)d_in[1];
  const float* Wloop = (const float*)d_in[2];
  const float* brel = (const float*)d_in[3];
  const float* Wg = (const float*)d_in[4];
  const float* al = (const float*)d_in[5];
  const float* ar = (const float*)d_in[6];
  const float* Wd = (const float*)d_in[7];
  const float* bd = (const float*)d_in[8];
  const int* src = (const int*)d_in[9];
  const int* dst = (const int*)d_in[10];
  const int* et = (const int*)d_in[11];
  const int* gids = (const int*)d_in[12];

  const int N = in_sizes[0] / DD;
  const int E = in_sizes[9];
  const int L = in_sizes[2] / (DD * DD);
  float* out = (float*)d_out;

  // ---- workspace layout ----
  float* wsf = (float*)d_ws;
  float* hA = wsf;                          // N*64
  float* hB = hA + (size_t)N * DD;          // N*64
  float* aggr = hB + (size_t)N * DD;        // N*256
  int* rowptr = (int*)(aggr + (size_t)N * 4 * DD);  // N+1
  int* cursor = rowptr + N + 1;             // N
  int* deg = cursor + N;                    // N
  int* srcet = deg + N;                     // E
  float* el = (float*)(srcet + E);          // N
  float* er = el + N;                       // N
  float* hg = aggr;                         // overlay: aggr dead after last dense

  dim3 b256(256);
  const int grid_dense = (N + 63) / 64;
  const int grid_e = (E + 255) / 256;
  const int grid_n4 = (N + 3) / 4;

  hipLaunchKernelGGL(init_out_k, dim3((out_size + 255) / 256), b256, 0, stream,
                     out, bd, out_size);

  // ---- CSR build ----
  hipMemsetAsync(deg, 0, (size_t)N * 4, stream);
  hipLaunchKernelGGL(k_deg, dim3(grid_e), b256, 0, stream, dst, deg, E);
  hipLaunchKernelGGL(k_scan, dim3(1), dim3(1024), 0, stream, deg, rowptr,
                     cursor, N, E);
  hipLaunchKernelGGL(k_fill, dim3(grid_e), b256, 0, stream, src, dst, et,
                     cursor, srcet, E);

  // ---- RGCN layers ----
  const float* cur = h0;
  float* nxt = hA;
  for (int l = 0; l < L; ++l) {
    hipLaunchKernelGGL(gather_rel, dim3(grid_n4), b256, 0, stream, cur, rowptr,
                       srcet, aggr, N, l > 0 ? 1 : 0);
    hipLaunchKernelGGL(rgcn_dense, dim3(grid_dense), b256, 0, stream, aggr, cur,
                       Wrel + (size_t)l * 4 * DD * DD,
                       Wloop + (size_t)l * DD * DD, brel + (size_t)l * DD, nxt,
                       N, l > 0 ? 1 : 0);
    cur = nxt;
    nxt = (cur == hA) ? hB : hA;
  }

  // ---- GAT ----
  float* zb = nxt;
  hipLaunchKernelGGL(gemm_relu64, dim3(grid_dense), b256, 0, stream, cur, Wg,
                     zb, N);
  hipLaunchKernelGGL(el_er_k, dim3(grid_n4), b256, 0, stream, zb, al, ar, el,
                     er, N);
  hipLaunchKernelGGL(gat_fused, dim3(grid_n4), b256, 0, stream, zb, el, er,
                     rowptr, srcet, hg, N);
  hipLaunchKernelGGL(pool_head, dim3(grid_n4), b256, 0, stream, hg, Wd, gids,
                     out, N);
}

// Round 3
// 1097.399 us; speedup vs baseline: 6.7716x; 1.2699x over previous
//
#include <hip/hip_runtime.h>

#define DD 64

// ================= CSR build =================
__global__ __launch_bounds__(256) void k_deg(const int* __restrict__ dst,
                                             int* __restrict__ deg, int E) {
  int e = blockIdx.x * 256 + threadIdx.x;
  if (e < E) atomicAdd(&deg[dst[e]], 1);
}

__global__ __launch_bounds__(1024) void k_scan(const int* __restrict__ deg,
                                               int* __restrict__ rowptr,
                                               int* __restrict__ cursor, int N,
                                               int E) {
  __shared__ int part[1024];
  const int t = threadIdx.x;
  const int C = (N + 1023) / 1024;
  const int b = t * C;
  const int e = min(b + C, N);
  int s = 0;
  for (int i = b; i < e; ++i) s += deg[i];
  part[t] = s;
  __syncthreads();
  if (t == 0) {
    int run = 0;
    for (int i = 0; i < 1024; ++i) {
      int v = part[i];
      part[i] = run;
      run += v;
    }
  }
  __syncthreads();
  int run = part[t];
  for (int i = b; i < e; ++i) {
    rowptr[i] = run;
    cursor[i] = run;
    run += deg[i];
  }
  if (t == 1023) rowptr[N] = E;
}

__global__ __launch_bounds__(256) void k_fill(const int* __restrict__ src,
                                              const int* __restrict__ dst,
                                              const int* __restrict__ et,
                                              int* __restrict__ cursor,
                                              int* __restrict__ srcet, int E) {
  int e = blockIdx.x * 256 + threadIdx.x;
  if (e >= E) return;
  int pos = atomicAdd(&cursor[dst[e]], 1);
  srcet[pos] = (src[e] << 2) | et[e];
}

// ================= per-node relation gather =================
// one wave per node; 4 groups of 16 lanes, each group = one edge in flight,
// each lane = one float4 chunk of the 64-float row.
__global__ __launch_bounds__(256) void gather_rel(
    const float* __restrict__ h, const int* __restrict__ rowptr,
    const int* __restrict__ srcet, float* __restrict__ aggr, int N,
    int relu_in) {
  const int n = blockIdx.x * 4 + (threadIdx.x >> 6);
  const int lane = threadIdx.x & 63;
  const int g = lane >> 4;    // edge slot 0..3
  const int t = lane & 15;    // float4 chunk 0..15
  if (n >= N) return;
  const int beg = rowptr[n], end = rowptr[n + 1];

  float4 a0 = make_float4(0.f, 0.f, 0.f, 0.f);
  float4 a1 = a0, a2 = a0, a3 = a0;

  for (int j = beg + g; j < end; j += 4) {
    const int se = srcet[j];            // 16 lanes same addr -> broadcast
    const int s = se >> 2;
    const int r = se & 3;
    float4 v = *(const float4*)(h + ((size_t)s << 6) + (t << 2));
    if (relu_in) {
      v.x = fmaxf(v.x, 0.f); v.y = fmaxf(v.y, 0.f);
      v.z = fmaxf(v.z, 0.f); v.w = fmaxf(v.w, 0.f);
    }
    if (r == 0) { a0.x += v.x; a0.y += v.y; a0.z += v.z; a0.w += v.w; }
    else if (r == 1) { a1.x += v.x; a1.y += v.y; a1.z += v.z; a1.w += v.w; }
    else if (r == 2) { a2.x += v.x; a2.y += v.y; a2.z += v.z; a2.w += v.w; }
    else { a3.x += v.x; a3.y += v.y; a3.z += v.z; a3.w += v.w; }
  }

  // combine the 4 lane groups (xor 16, xor 32)
#pragma unroll
  for (int off = 16; off <= 32; off <<= 1) {
    a0.x += __shfl_xor(a0.x, off); a0.y += __shfl_xor(a0.y, off);
    a0.z += __shfl_xor(a0.z, off); a0.w += __shfl_xor(a0.w, off);
    a1.x += __shfl_xor(a1.x, off); a1.y += __shfl_xor(a1.y, off);
    a1.z += __shfl_xor(a1.z, off); a1.w += __shfl_xor(a1.w, off);
    a2.x += __shfl_xor(a2.x, off); a2.y += __shfl_xor(a2.y, off);
    a2.z += __shfl_xor(a2.z, off); a2.w += __shfl_xor(a2.w, off);
    a3.x += __shfl_xor(a3.x, off); a3.y += __shfl_xor(a3.y, off);
    a3.z += __shfl_xor(a3.z, off); a3.w += __shfl_xor(a3.w, off);
  }

  // group g stores relation g's chunk t
  const float4 res = (g == 0) ? a0 : (g == 1) ? a1 : (g == 2) ? a2 : a3;
  *(float4*)(aggr + ((size_t)n << 8) + (g << 6) + (t << 2)) = res;
}

// ================= dense: hnext = sum_r aggr[r]@Wrel[r] + relu?(h)@Wloop + brel ==========
__global__ __launch_bounds__(256) void rgcn_dense(
    const float* __restrict__ aggr, const float* __restrict__ hin,
    const float* __restrict__ Wrel, const float* __restrict__ Wloop,
    const float* __restrict__ brel, float* __restrict__ hnext, int N,
    int relu_in) {
  const int lane = threadIdx.x & 63;
  const int wv = threadIdx.x >> 6;
  const int c0 = __builtin_amdgcn_readfirstlane(wv << 4);
  const int n = blockIdx.x * 64 + lane;

  float acc[16];
#pragma unroll
  for (int jj = 0; jj < 16; ++jj) acc[jj] = brel[c0 + jj];

  float in[DD];
#pragma unroll 1
  for (int m = 0; m < 5; ++m) {
    const float* __restrict__ W =
        (m < 4) ? (Wrel + (size_t)m * DD * DD) : Wloop;
    if (n < N) {
      const float4* p = (m < 4)
                            ? (const float4*)(aggr + ((size_t)n << 8) + (m << 6))
                            : (const float4*)(hin + ((size_t)n << 6));
#pragma unroll
      for (int t = 0; t < DD / 4; ++t) {
        float4 v = p[t];
        if (m == 4 && relu_in) {
          v.x = fmaxf(v.x, 0.f); v.y = fmaxf(v.y, 0.f);
          v.z = fmaxf(v.z, 0.f); v.w = fmaxf(v.w, 0.f);
        }
        in[4 * t + 0] = v.x; in[4 * t + 1] = v.y;
        in[4 * t + 2] = v.z; in[4 * t + 3] = v.w;
      }
    } else {
#pragma unroll
      for (int t = 0; t < DD; ++t) in[t] = 0.f;
    }
#pragma unroll
    for (int k = 0; k < DD; ++k) {
      const float hk = in[k];
#pragma unroll
      for (int jj = 0; jj < 16; ++jj)
        acc[jj] = fmaf(hk, W[k * DD + c0 + jj], acc[jj]);
    }
  }
  if (n < N) {
    float* o = hnext + ((size_t)n << 6) + c0;
#pragma unroll
    for (int jj = 0; jj < 16; jj += 4)
      *(float4*)(o + jj) =
          make_float4(acc[jj], acc[jj + 1], acc[jj + 2], acc[jj + 3]);
  }
}

// ================= z = relu(h) @ Wg =================
__global__ __launch_bounds__(256) void gemm_relu64(const float* __restrict__ hin,
                                                   const float* __restrict__ W,
                                                   float* __restrict__ out,
                                                   int N) {
  const int lane = threadIdx.x & 63;
  const int wv = threadIdx.x >> 6;
  const int c0 = __builtin_amdgcn_readfirstlane(wv << 4);
  const int n = blockIdx.x * 64 + lane;

  float h[DD];
  if (n < N) {
    const float4* hp = (const float4*)(hin + (size_t)n * DD);
#pragma unroll
    for (int t = 0; t < DD / 4; ++t) {
      float4 v = hp[t];
      v.x = fmaxf(v.x, 0.f); v.y = fmaxf(v.y, 0.f);
      v.z = fmaxf(v.z, 0.f); v.w = fmaxf(v.w, 0.f);
      h[4 * t + 0] = v.x; h[4 * t + 1] = v.y;
      h[4 * t + 2] = v.z; h[4 * t + 3] = v.w;
    }
  } else {
#pragma unroll
    for (int t = 0; t < DD; ++t) h[t] = 0.f;
  }
  float acc[16];
#pragma unroll
  for (int j = 0; j < 16; ++j) acc[j] = 0.f;
#pragma unroll
  for (int k = 0; k < DD; ++k) {
    const float hk = h[k];
#pragma unroll
    for (int j = 0; j < 16; ++j)
      acc[j] = fmaf(hk, W[k * DD + c0 + j], acc[j]);
  }
  if (n < N) {
    float* o = out + ((size_t)n << 6) + c0;
#pragma unroll
    for (int j = 0; j < 16; j += 4)
      *(float4*)(o + j) =
          make_float4(acc[j], acc[j + 1], acc[j + 2], acc[j + 3]);
  }
}

// ================= GAT: el/er per node =================
__global__ __launch_bounds__(256) void el_er_k(
    const float* __restrict__ z, const float* __restrict__ al,
    const float* __restrict__ ar, float* __restrict__ el,
    float* __restrict__ er, int N) {
  int n = blockIdx.x * 4 + (threadIdx.x >> 6);
  int lane = threadIdx.x & 63;
  if (n >= N) return;
  float v = z[(size_t)n * DD + lane];
  float pl = v * al[lane];
  float pr = v * ar[lane];
#pragma unroll
  for (int off = 32; off > 0; off >>= 1) {
    pl += __shfl_down(pl, off);
    pr += __shfl_down(pr, off);
  }
  if (lane == 0) {
    el[n] = pl;
    er[n] = pr;
  }
}

// ================= fused GAT aggregation (per destination node) =================
// phase A: edge-per-lane online softmax (m, den). phase B: 4x16 weighted gather.
__global__ __launch_bounds__(256) void gat_fused(
    const float* __restrict__ z, const float* __restrict__ el,
    const float* __restrict__ er, const int* __restrict__ rowptr,
    const int* __restrict__ srcet, float* __restrict__ hg, int N) {
  const int n = blockIdx.x * 4 + (threadIdx.x >> 6);
  const int lane = threadIdx.x & 63;
  const int g = lane >> 4;
  const int t = lane & 15;
  if (n >= N) return;
  const int beg = rowptr[n], end = rowptr[n + 1];
  const float ern = er[n];

  // phase A: online (m, den) with 64 edges in flight
  float m = -1e30f, den = 0.f;
  for (int j = beg + lane; j < end; j += 64) {
    const int s = srcet[j] >> 2;
    float x = el[s] + ern;
    x = (x > 0.f) ? x : 0.2f * x;
    if (x > m) {
      den *= __expf(m - x);
      m = x;
    }
    den += __expf(x - m);
  }
#pragma unroll
  for (int off = 1; off < 64; off <<= 1) {
    float mo = __shfl_xor(m, off);
    float dn = __shfl_xor(den, off);
    float M = fmaxf(m, mo);
    den = den * __expf(m - M) + dn * __expf(mo - M);
    m = M;
  }

  // phase B: weighted gather, 4 edges in flight
  float4 num = make_float4(0.f, 0.f, 0.f, 0.f);
  for (int j = beg + g; j < end; j += 4) {
    const int se = srcet[j];
    const int s = se >> 2;
    float x = el[s] + ern;
    x = (x > 0.f) ? x : 0.2f * x;
    const float w = __expf(x - m);
    float4 v = *(const float4*)(z + ((size_t)s << 6) + (t << 2));
    num.x = fmaf(w, v.x, num.x);
    num.y = fmaf(w, v.y, num.y);
    num.z = fmaf(w, v.z, num.z);
    num.w = fmaf(w, v.w, num.w);
  }
#pragma unroll
  for (int off = 16; off <= 32; off <<= 1) {
    num.x += __shfl_xor(num.x, off);
    num.y += __shfl_xor(num.y, off);
    num.z += __shfl_xor(num.z, off);
    num.w += __shfl_xor(num.w, off);
  }
  if (g == 0) {
    const float inv = 1.f / fmaxf(den, 1e-9f);
    float4 o = make_float4(num.x * inv, num.y * inv, num.z * inv, num.w * inv);
    *(float4*)(hg + ((size_t)n << 6) + (t << 2)) = o;
  }
}

// ================= pooled head =================
__global__ __launch_bounds__(256) void pool_head(
    const float* __restrict__ hg, const float* __restrict__ Wd,
    const int* __restrict__ gids, float* __restrict__ out, int N) {
  int n = blockIdx.x * 4 + (threadIdx.x >> 6);
  int lane = threadIdx.x & 63;
  if (n >= N) return;
  float v = hg[(size_t)n * DD + lane] * Wd[lane];
#pragma unroll
  for (int off = 32; off > 0; off >>= 1) v += __shfl_down(v, off);
  if (lane == 0) unsafeAtomicAdd(out + gids[n], v);
}

__global__ void init_out_k(float* out, const float* bd, int n) {
  int i = blockIdx.x * blockDim.x + threadIdx.x;
  if (i < n) out[i] = bd[0];
}

// ================= launch =================
extern "C" void kernel_launch(void* const* d_in, const int* in_sizes, int n_in,
                              void* d_out, int out_size, void* d_ws,
                              size_t ws_size, hipStream_t stream) {
  const float* h0 = (const float*)d_in[0];
  const float* Wrel = (const float*)d_in[1];
  const float* Wloop = (const float*)d_in[2];
  const float* brel = (const float*)d_in[3];
  const float* Wg = (const float*)d_in[4];
  const float* al = (const float*)d_in[5];
  const float* ar = (const float*)d_in[6];
  const float* Wd = (const float*)d_in[7];
  const float* bd = (const float*)d_in[8];
  const int* src = (const int*)d_in[9];
  const int* dst = (const int*)d_in[10];
  const int* et = (const int*)d_in[11];
  const int* gids = (const int*)d_in[12];

  const int N = in_sizes[0] / DD;
  const int E = in_sizes[9];
  const int L = in_sizes[2] / (DD * DD);
  float* out = (float*)d_out;

  // ---- workspace layout ----
  float* wsf = (float*)d_ws;
  float* hA = wsf;                          // N*64
  float* hB = hA + (size_t)N * DD;          // N*64
  float* aggr = hB + (size_t)N * DD;        // N*256
  int* rowptr = (int*)(aggr + (size_t)N * 4 * DD);  // N+1
  int* cursor = rowptr + N + 1;             // N
  int* deg = cursor + N;                    // N
  int* srcet = deg + N;                     // E
  float* el = (float*)(srcet + E);          // N
  float* er = el + N;                       // N
  float* hg = aggr;                         // overlay: aggr dead after last dense

  dim3 b256(256);
  const int grid_dense = (N + 63) / 64;
  const int grid_e = (E + 255) / 256;
  const int grid_n4 = (N + 3) / 4;

  hipLaunchKernelGGL(init_out_k, dim3((out_size + 255) / 256), b256, 0, stream,
                     out, bd, out_size);

  // ---- CSR build ----
  hipMemsetAsync(deg, 0, (size_t)N * 4, stream);
  hipLaunchKernelGGL(k_deg, dim3(grid_e), b256, 0, stream, dst, deg, E);
  hipLaunchKernelGGL(k_scan, dim3(1), dim3(1024), 0, stream, deg, rowptr,
                     cursor, N, E);
  hipLaunchKernelGGL(k_fill, dim3(grid_e), b256, 0, stream, src, dst, et,
                     cursor, srcet, E);

  // ---- RGCN layers ----
  const float* cur = h0;
  float* nxt = hA;
  for (int l = 0; l < L; ++l) {
    hipLaunchKernelGGL(gather_rel, dim3(grid_n4), b256, 0, stream, cur, rowptr,
                       srcet, aggr, N, l > 0 ? 1 : 0);
    hipLaunchKernelGGL(rgcn_dense, dim3(grid_dense), b256, 0, stream, aggr, cur,
                       Wrel + (size_t)l * 4 * DD * DD,
                       Wloop + (size_t)l * DD * DD, brel + (size_t)l * DD, nxt,
                       N, l > 0 ? 1 : 0);
    cur = nxt;
    nxt = (cur == hA) ? hB : hA;
  }

  // ---- GAT ----
  float* zb = nxt;
  hipLaunchKernelGGL(gemm_relu64, dim3(grid_dense), b256, 0, stream, cur, Wg,
                     zb, N);
  hipLaunchKernelGGL(el_er_k, dim3(grid_n4), b256, 0, stream, zb, al, ar, el,
                     er, N);
  hipLaunchKernelGGL(gat_fused, dim3(grid_n4), b256, 0, stream, zb, el, er,
                     rowptr, srcet, hg, N);
  hipLaunchKernelGGL(pool_head, dim3(grid_n4), b256, 0, stream, hg, Wd, gids,
                     out, N);
}

// Round 4
// 945.513 us; speedup vs baseline: 7.8594x; 1.1606x over previous
//
#include <hip/hip_runtime.h>

#define DD 64
#define POOL_NPB 512  // nodes per block in pool_head2

// ================= CSR build =================
__global__ __launch_bounds__(256) void k_deg(const int* __restrict__ dst,
                                             int* __restrict__ deg, int E) {
  int e = blockIdx.x * 256 + threadIdx.x;
  if (e < E) atomicAdd(&deg[dst[e]], 1);
}

__global__ __launch_bounds__(1024) void k_scan(const int* __restrict__ deg,
                                               int* __restrict__ rowptr,
                                               int* __restrict__ cursor, int N,
                                               int E) {
  __shared__ int part[1024];
  const int t = threadIdx.x;
  const int C = (N + 1023) / 1024;
  const int b = t * C;
  const int e = min(b + C, N);
  int s = 0;
  for (int i = b; i < e; ++i) s += deg[i];
  part[t] = s;
  __syncthreads();
  if (t == 0) {
    int run = 0;
    for (int i = 0; i < 1024; ++i) {
      int v = part[i];
      part[i] = run;
      run += v;
    }
  }
  __syncthreads();
  int run = part[t];
  for (int i = b; i < e; ++i) {
    rowptr[i] = run;
    cursor[i] = run;
    run += deg[i];
  }
  if (t == 1023) rowptr[N] = E;
}

__global__ __launch_bounds__(256) void k_fill(const int* __restrict__ src,
                                              const int* __restrict__ dst,
                                              const int* __restrict__ et,
                                              int* __restrict__ cursor,
                                              int* __restrict__ srcet, int E) {
  int e = blockIdx.x * 256 + threadIdx.x;
  if (e >= E) return;
  int pos = atomicAdd(&cursor[dst[e]], 1);
  srcet[pos] = (src[e] << 2) | et[e];
}

// ================= per-node relation gather =================
__global__ __launch_bounds__(256) void gather_rel(
    const float* __restrict__ h, const int* __restrict__ rowptr,
    const int* __restrict__ srcet, float* __restrict__ aggr, int N,
    int relu_in) {
  const int n = blockIdx.x * 4 + (threadIdx.x >> 6);
  const int lane = threadIdx.x & 63;
  const int g = lane >> 4;    // edge slot 0..3
  const int t = lane & 15;    // float4 chunk 0..15
  if (n >= N) return;
  const int beg = rowptr[n], end = rowptr[n + 1];

  float4 a0 = make_float4(0.f, 0.f, 0.f, 0.f);
  float4 a1 = a0, a2 = a0, a3 = a0;

  for (int j = beg + g; j < end; j += 4) {
    const int se = srcet[j];
    const int s = se >> 2;
    const int r = se & 3;
    float4 v = *(const float4*)(h + ((size_t)s << 6) + (t << 2));
    if (relu_in) {
      v.x = fmaxf(v.x, 0.f); v.y = fmaxf(v.y, 0.f);
      v.z = fmaxf(v.z, 0.f); v.w = fmaxf(v.w, 0.f);
    }
    if (r == 0) { a0.x += v.x; a0.y += v.y; a0.z += v.z; a0.w += v.w; }
    else if (r == 1) { a1.x += v.x; a1.y += v.y; a1.z += v.z; a1.w += v.w; }
    else if (r == 2) { a2.x += v.x; a2.y += v.y; a2.z += v.z; a2.w += v.w; }
    else { a3.x += v.x; a3.y += v.y; a3.z += v.z; a3.w += v.w; }
  }

#pragma unroll
  for (int off = 16; off <= 32; off <<= 1) {
    a0.x += __shfl_xor(a0.x, off); a0.y += __shfl_xor(a0.y, off);
    a0.z += __shfl_xor(a0.z, off); a0.w += __shfl_xor(a0.w, off);
    a1.x += __shfl_xor(a1.x, off); a1.y += __shfl_xor(a1.y, off);
    a1.z += __shfl_xor(a1.z, off); a1.w += __shfl_xor(a1.w, off);
    a2.x += __shfl_xor(a2.x, off); a2.y += __shfl_xor(a2.y, off);
    a2.z += __shfl_xor(a2.z, off); a2.w += __shfl_xor(a2.w, off);
    a3.x += __shfl_xor(a3.x, off); a3.y += __shfl_xor(a3.y, off);
    a3.z += __shfl_xor(a3.z, off); a3.w += __shfl_xor(a3.w, off);
  }

  const float4 res = (g == 0) ? a0 : (g == 1) ? a1 : (g == 2) ? a2 : a3;
  *(float4*)(aggr + ((size_t)n << 8) + (g << 6) + (t << 2)) = res;
}

// ================= dense: hnext = sum_r aggr[r]@Wrel[r] + relu?(h)@Wloop + brel ==========
__global__ __launch_bounds__(256) void rgcn_dense(
    const float* __restrict__ aggr, const float* __restrict__ hin,
    const float* __restrict__ Wrel, const float* __restrict__ Wloop,
    const float* __restrict__ brel, float* __restrict__ hnext, int N,
    int relu_in) {
  const int lane = threadIdx.x & 63;
  const int wv = threadIdx.x >> 6;
  const int c0 = __builtin_amdgcn_readfirstlane(wv << 4);
  const int n = blockIdx.x * 64 + lane;

  float acc[16];
#pragma unroll
  for (int jj = 0; jj < 16; ++jj) acc[jj] = brel[c0 + jj];

  float in[DD];
#pragma unroll 1
  for (int m = 0; m < 5; ++m) {
    const float* __restrict__ W =
        (m < 4) ? (Wrel + (size_t)m * DD * DD) : Wloop;
    if (n < N) {
      const float4* p = (m < 4)
                            ? (const float4*)(aggr + ((size_t)n << 8) + (m << 6))
                            : (const float4*)(hin + ((size_t)n << 6));
#pragma unroll
      for (int t = 0; t < DD / 4; ++t) {
        float4 v = p[t];
        if (m == 4 && relu_in) {
          v.x = fmaxf(v.x, 0.f); v.y = fmaxf(v.y, 0.f);
          v.z = fmaxf(v.z, 0.f); v.w = fmaxf(v.w, 0.f);
        }
        in[4 * t + 0] = v.x; in[4 * t + 1] = v.y;
        in[4 * t + 2] = v.z; in[4 * t + 3] = v.w;
      }
    } else {
#pragma unroll
      for (int t = 0; t < DD; ++t) in[t] = 0.f;
    }
#pragma unroll
    for (int k = 0; k < DD; ++k) {
      const float hk = in[k];
#pragma unroll
      for (int jj = 0; jj < 16; ++jj)
        acc[jj] = fmaf(hk, W[k * DD + c0 + jj], acc[jj]);
    }
  }
  if (n < N) {
    float* o = hnext + ((size_t)n << 6) + c0;
#pragma unroll
    for (int jj = 0; jj < 16; jj += 4)
      *(float4*)(o + jj) =
          make_float4(acc[jj], acc[jj + 1], acc[jj + 2], acc[jj + 3]);
  }
}

// ================= z = relu(h) @ Wg =================
__global__ __launch_bounds__(256) void gemm_relu64(const float* __restrict__ hin,
                                                   const float* __restrict__ W,
                                                   float* __restrict__ out,
                                                   int N) {
  const int lane = threadIdx.x & 63;
  const int wv = threadIdx.x >> 6;
  const int c0 = __builtin_amdgcn_readfirstlane(wv << 4);
  const int n = blockIdx.x * 64 + lane;

  float h[DD];
  if (n < N) {
    const float4* hp = (const float4*)(hin + (size_t)n * DD);
#pragma unroll
    for (int t = 0; t < DD / 4; ++t) {
      float4 v = hp[t];
      v.x = fmaxf(v.x, 0.f); v.y = fmaxf(v.y, 0.f);
      v.z = fmaxf(v.z, 0.f); v.w = fmaxf(v.w, 0.f);
      h[4 * t + 0] = v.x; h[4 * t + 1] = v.y;
      h[4 * t + 2] = v.z; h[4 * t + 3] = v.w;
    }
  } else {
#pragma unroll
    for (int t = 0; t < DD; ++t) h[t] = 0.f;
  }
  float acc[16];
#pragma unroll
  for (int j = 0; j < 16; ++j) acc[j] = 0.f;
#pragma unroll
  for (int k = 0; k < DD; ++k) {
    const float hk = h[k];
#pragma unroll
    for (int j = 0; j < 16; ++j)
      acc[j] = fmaf(hk, W[k * DD + c0 + j], acc[j]);
  }
  if (n < N) {
    float* o = out + ((size_t)n << 6) + c0;
#pragma unroll
    for (int j = 0; j < 16; j += 4)
      *(float4*)(o + j) =
          make_float4(acc[j], acc[j + 1], acc[j + 2], acc[j + 3]);
  }
}

// ================= GAT: el/er per node =================
__global__ __launch_bounds__(256) void el_er_k(
    const float* __restrict__ z, const float* __restrict__ al,
    const float* __restrict__ ar, float* __restrict__ el,
    float* __restrict__ er, int N) {
  int n = blockIdx.x * 4 + (threadIdx.x >> 6);
  int lane = threadIdx.x & 63;
  if (n >= N) return;
  float v = z[(size_t)n * DD + lane];
  float pl = v * al[lane];
  float pr = v * ar[lane];
#pragma unroll
  for (int off = 32; off > 0; off >>= 1) {
    pl += __shfl_down(pl, off);
    pr += __shfl_down(pr, off);
  }
  if (lane == 0) {
    el[n] = pl;
    er[n] = pr;
  }
}

// ================= fused GAT aggregation (per destination node) =================
__global__ __launch_bounds__(256) void gat_fused(
    const float* __restrict__ z, const float* __restrict__ el,
    const float* __restrict__ er, const int* __restrict__ rowptr,
    const int* __restrict__ srcet, float* __restrict__ hg, int N) {
  const int n = blockIdx.x * 4 + (threadIdx.x >> 6);
  const int lane = threadIdx.x & 63;
  const int g = lane >> 4;
  const int t = lane & 15;
  if (n >= N) return;
  const int beg = rowptr[n], end = rowptr[n + 1];
  const float ern = er[n];

  // phase A: online (m, den) with 64 edges in flight
  float m = -1e30f, den = 0.f;
  for (int j = beg + lane; j < end; j += 64) {
    const int s = srcet[j] >> 2;
    float x = el[s] + ern;
    x = (x > 0.f) ? x : 0.2f * x;
    if (x > m) {
      den *= __expf(m - x);
      m = x;
    }
    den += __expf(x - m);
  }
#pragma unroll
  for (int off = 1; off < 64; off <<= 1) {
    float mo = __shfl_xor(m, off);
    float dn = __shfl_xor(den, off);
    float M = fmaxf(m, mo);
    den = den * __expf(m - M) + dn * __expf(mo - M);
    m = M;
  }

  // phase B: weighted gather, 4 edges in flight
  float4 num = make_float4(0.f, 0.f, 0.f, 0.f);
  for (int j = beg + g; j < end; j += 4) {
    const int se = srcet[j];
    const int s = se >> 2;
    float x = el[s] + ern;
    x = (x > 0.f) ? x : 0.2f * x;
    const float w = __expf(x - m);
    float4 v = *(const float4*)(z + ((size_t)s << 6) + (t << 2));
    num.x = fmaf(w, v.x, num.x);
    num.y = fmaf(w, v.y, num.y);
    num.z = fmaf(w, v.z, num.z);
    num.w = fmaf(w, v.w, num.w);
  }
#pragma unroll
  for (int off = 16; off <= 32; off <<= 1) {
    num.x += __shfl_xor(num.x, off);
    num.y += __shfl_xor(num.y, off);
    num.z += __shfl_xor(num.z, off);
    num.w += __shfl_xor(num.w, off);
  }
  if (g == 0) {
    const float inv = 1.f / fmaxf(den, 1e-9f);
    float4 o = make_float4(num.x * inv, num.y * inv, num.z * inv, num.w * inv);
    *(float4*)(hg + ((size_t)n << 6) + (t << 2)) = o;
  }
}

// ================= pooled head, two-level (LDS per-gid table, sorted gids) =========
// block = 256 threads, POOL_NPB nodes. lane layout: sub = lane&3 (col chunk),
// idx = lane>>2 (node within 16-node group) -> fully coalesced 1KB/wave reads.
__global__ __launch_bounds__(256) void pool_head2(
    const float* __restrict__ hg, const float* __restrict__ Wd,
    const int* __restrict__ gids, float* __restrict__ out, int N, int B) {
  __shared__ float acc[1024];
  for (int i = threadIdx.x; i < B; i += 256) acc[i] = 0.f;
  __syncthreads();

  const int wv = threadIdx.x >> 6;
  const int lane = threadIdx.x & 63;
  const int sub = lane & 3;
  const int idx = lane >> 2;

  const float4 w0 = *(const float4*)(Wd + (sub << 4) + 0);
  const float4 w1 = *(const float4*)(Wd + (sub << 4) + 4);
  const float4 w2 = *(const float4*)(Wd + (sub << 4) + 8);
  const float4 w3 = *(const float4*)(Wd + (sub << 4) + 12);

  const int base0 = blockIdx.x * POOL_NPB;
#pragma unroll 1
  for (int it = 0; it < POOL_NPB / 64; ++it) {
    const int n = base0 + it * 64 + wv * 16 + idx;
    if (n < N) {
      const float* p = hg + ((size_t)n << 6) + (sub << 4);
      const float4 v0 = *(const float4*)(p + 0);
      const float4 v1 = *(const float4*)(p + 4);
      const float4 v2 = *(const float4*)(p + 8);
      const float4 v3 = *(const float4*)(p + 12);
      float s = v0.x * w0.x + v0.y * w0.y + v0.z * w0.z + v0.w * w0.w;
      s = fmaf(v1.x, w1.x, s); s = fmaf(v1.y, w1.y, s);
      s = fmaf(v1.z, w1.z, s); s = fmaf(v1.w, w1.w, s);
      s = fmaf(v2.x, w2.x, s); s = fmaf(v2.y, w2.y, s);
      s = fmaf(v2.z, w2.z, s); s = fmaf(v2.w, w2.w, s);
      s = fmaf(v3.x, w3.x, s); s = fmaf(v3.y, w3.y, s);
      s = fmaf(v3.z, w3.z, s); s = fmaf(v3.w, w3.w, s);
      s += __shfl_xor(s, 1);
      s += __shfl_xor(s, 2);
      if (sub == 0) atomicAdd(&acc[gids[n]], s);
    }
  }
  __syncthreads();
  for (int i = threadIdx.x; i < B; i += 256) {
    const float v = acc[i];
    if (v != 0.f) unsafeAtomicAdd(out + i, v);  // skipping exact zeros is a no-op add
  }
}

__global__ void init_out_k(float* out, const float* bd, int n) {
  int i = blockIdx.x * blockDim.x + threadIdx.x;
  if (i < n) out[i] = bd[0];
}

// ================= launch =================
extern "C" void kernel_launch(void* const* d_in, const int* in_sizes, int n_in,
                              void* d_out, int out_size, void* d_ws,
                              size_t ws_size, hipStream_t stream) {
  const float* h0 = (const float*)d_in[0];
  const float* Wrel = (const float*)d_in[1];
  const float* Wloop = (const float*)d_in[2];
  const float* brel = (const float*)d_in[3];
  const float* Wg = (const float*)d_in[4];
  const float* al = (const float*)d_in[5];
  const float* ar = (const float*)d_in[6];
  const float* Wd = (const float*)d_in[7];
  const float* bd = (const float*)d_in[8];
  const int* src = (const int*)d_in[9];
  const int* dst = (const int*)d_in[10];
  const int* et = (const int*)d_in[11];
  const int* gids = (const int*)d_in[12];

  const int N = in_sizes[0] / DD;
  const int E = in_sizes[9];
  const int L = in_sizes[2] / (DD * DD);
  float* out = (float*)d_out;

  // ---- workspace layout ----
  float* wsf = (float*)d_ws;
  float* hA = wsf;                          // N*64
  float* hB = hA + (size_t)N * DD;          // N*64
  float* aggr = hB + (size_t)N * DD;        // N*256
  int* rowptr = (int*)(aggr + (size_t)N * 4 * DD);  // N+1
  int* cursor = rowptr + N + 1;             // N
  int* deg = cursor + N;                    // N
  int* srcet = deg + N;                     // E
  float* el = (float*)(srcet + E);          // N
  float* er = el + N;                       // N
  float* hg = aggr;                         // overlay: aggr dead after last dense

  dim3 b256(256);
  const int grid_dense = (N + 63) / 64;
  const int grid_e = (E + 255) / 256;
  const int grid_n4 = (N + 3) / 4;

  hipLaunchKernelGGL(init_out_k, dim3((out_size + 255) / 256), b256, 0, stream,
                     out, bd, out_size);

  // ---- CSR build ----
  hipMemsetAsync(deg, 0, (size_t)N * 4, stream);
  hipLaunchKernelGGL(k_deg, dim3(grid_e), b256, 0, stream, dst, deg, E);
  hipLaunchKernelGGL(k_scan, dim3(1), dim3(1024), 0, stream, deg, rowptr,
                     cursor, N, E);
  hipLaunchKernelGGL(k_fill, dim3(grid_e), b256, 0, stream, src, dst, et,
                     cursor, srcet, E);

  // ---- RGCN layers ----
  const float* cur = h0;
  float* nxt = hA;
  for (int l = 0; l < L; ++l) {
    hipLaunchKernelGGL(gather_rel, dim3(grid_n4), b256, 0, stream, cur, rowptr,
                       srcet, aggr, N, l > 0 ? 1 : 0);
    hipLaunchKernelGGL(rgcn_dense, dim3(grid_dense), b256, 0, stream, aggr, cur,
                       Wrel + (size_t)l * 4 * DD * DD,
                       Wloop + (size_t)l * DD * DD, brel + (size_t)l * DD, nxt,
                       N, l > 0 ? 1 : 0);
    cur = nxt;
    nxt = (cur == hA) ? hB : hA;
  }

  // ---- GAT ----
  float* zb = nxt;
  hipLaunchKernelGGL(gemm_relu64, dim3(grid_dense), b256, 0, stream, cur, Wg,
                     zb, N);
  hipLaunchKernelGGL(el_er_k, dim3(grid_n4), b256, 0, stream, zb, al, ar, el,
                     er, N);
  hipLaunchKernelGGL(gat_fused, dim3(grid_n4), b256, 0, stream, zb, el, er,
                     rowptr, srcet, hg, N);

  const int grid_pool = (N + POOL_NPB - 1) / POOL_NPB;
  hipLaunchKernelGGL(pool_head2, dim3(grid_pool), b256, 0, stream, hg, Wd, gids,
                     out, N, out_size);
}

// Round 5
// 833.094 us; speedup vs baseline: 8.9199x; 1.1349x over previous
//
#include <hip/hip_runtime.h>

#define DD 64
#define POOL_NPB 512  // nodes per block in pool_head2

// ================= CSR build =================
__global__ __launch_bounds__(256) void k_deg(const int* __restrict__ dst,
                                             int* __restrict__ deg, int E) {
  int e = blockIdx.x * 256 + threadIdx.x;
  if (e < E) atomicAdd(&deg[dst[e]], 1);
}

// ---- 3-phase device-wide exclusive scan of deg -> rowptr/cursor ----
__global__ __launch_bounds__(256) void k_scan1(const int* __restrict__ deg,
                                               int* __restrict__ partials,
                                               int N) {
  __shared__ int s[256];
  const int t = threadIdx.x;
  const int i = blockIdx.x * 256 + t;
  s[t] = (i < N) ? deg[i] : 0;
  __syncthreads();
#pragma unroll
  for (int off = 128; off > 0; off >>= 1) {
    if (t < off) s[t] += s[t + off];
    __syncthreads();
  }
  if (t == 0) partials[blockIdx.x] = s[0];
}

__global__ __launch_bounds__(256) void k_scan2(int* __restrict__ partials,
                                               int nb) {
  __shared__ int s[256];
  const int t = threadIdx.x;
  const int v = (t < nb) ? partials[t] : 0;
  s[t] = v;
  __syncthreads();
#pragma unroll
  for (int off = 1; off < 256; off <<= 1) {
    const int add = (t >= off) ? s[t - off] : 0;
    __syncthreads();
    s[t] += add;
    __syncthreads();
  }
  if (t < nb) partials[t] = s[t] - v;  // exclusive
}

__global__ __launch_bounds__(256) void k_scan3(const int* __restrict__ deg,
                                               const int* __restrict__ partials,
                                               int* __restrict__ rowptr,
                                               int* __restrict__ cursor, int N,
                                               int E) {
  __shared__ int s[256];
  const int t = threadIdx.x;
  const int i = blockIdx.x * 256 + t;
  const int v = (i < N) ? deg[i] : 0;
  s[t] = v;
  __syncthreads();
#pragma unroll
  for (int off = 1; off < 256; off <<= 1) {
    const int add = (t >= off) ? s[t - off] : 0;
    __syncthreads();
    s[t] += add;
    __syncthreads();
  }
  if (i < N) {
    const int ex = partials[blockIdx.x] + s[t] - v;
    rowptr[i] = ex;
    cursor[i] = ex;
    if (i == N - 1) rowptr[N] = E;
  }
}

__global__ __launch_bounds__(256) void k_fill(const int* __restrict__ src,
                                              const int* __restrict__ dst,
                                              const int* __restrict__ et,
                                              int* __restrict__ cursor,
                                              int* __restrict__ srcet, int E) {
  int e = blockIdx.x * 256 + threadIdx.x;
  if (e >= E) return;
  int pos = atomicAdd(&cursor[dst[e]], 1);
  srcet[pos] = (src[e] << 2) | et[e];
}

// ================= per-node relation gather =================
__global__ __launch_bounds__(256) void gather_rel(
    const float* __restrict__ h, const int* __restrict__ rowptr,
    const int* __restrict__ srcet, float* __restrict__ aggr, int N,
    int relu_in) {
  const int n = blockIdx.x * 4 + (threadIdx.x >> 6);
  const int lane = threadIdx.x & 63;
  const int g = lane >> 4;    // edge slot 0..3
  const int t = lane & 15;    // float4 chunk 0..15
  if (n >= N) return;
  const int beg = rowptr[n], end = rowptr[n + 1];

  float4 a0 = make_float4(0.f, 0.f, 0.f, 0.f);
  float4 a1 = a0, a2 = a0, a3 = a0;

  for (int j = beg + g; j < end; j += 4) {
    const int se = srcet[j];
    const int s = se >> 2;
    const int r = se & 3;
    float4 v = *(const float4*)(h + ((size_t)s << 6) + (t << 2));
    if (relu_in) {
      v.x = fmaxf(v.x, 0.f); v.y = fmaxf(v.y, 0.f);
      v.z = fmaxf(v.z, 0.f); v.w = fmaxf(v.w, 0.f);
    }
    if (r == 0) { a0.x += v.x; a0.y += v.y; a0.z += v.z; a0.w += v.w; }
    else if (r == 1) { a1.x += v.x; a1.y += v.y; a1.z += v.z; a1.w += v.w; }
    else if (r == 2) { a2.x += v.x; a2.y += v.y; a2.z += v.z; a2.w += v.w; }
    else { a3.x += v.x; a3.y += v.y; a3.z += v.z; a3.w += v.w; }
  }

#pragma unroll
  for (int off = 16; off <= 32; off <<= 1) {
    a0.x += __shfl_xor(a0.x, off); a0.y += __shfl_xor(a0.y, off);
    a0.z += __shfl_xor(a0.z, off); a0.w += __shfl_xor(a0.w, off);
    a1.x += __shfl_xor(a1.x, off); a1.y += __shfl_xor(a1.y, off);
    a1.z += __shfl_xor(a1.z, off); a1.w += __shfl_xor(a1.w, off);
    a2.x += __shfl_xor(a2.x, off); a2.y += __shfl_xor(a2.y, off);
    a2.z += __shfl_xor(a2.z, off); a2.w += __shfl_xor(a2.w, off);
    a3.x += __shfl_xor(a3.x, off); a3.y += __shfl_xor(a3.y, off);
    a3.z += __shfl_xor(a3.z, off); a3.w += __shfl_xor(a3.w, off);
  }

  const float4 res = (g == 0) ? a0 : (g == 1) ? a1 : (g == 2) ? a2 : a3;
  *(float4*)(aggr + ((size_t)n << 8) + (g << 6) + (t << 2)) = res;
}

// ================= dense: hnext = sum_r aggr[r]@Wrel[r] + relu?(h)@Wloop + brel ==========
__global__ __launch_bounds__(256) void rgcn_dense(
    const float* __restrict__ aggr, const float* __restrict__ hin,
    const float* __restrict__ Wrel, const float* __restrict__ Wloop,
    const float* __restrict__ brel, float* __restrict__ hnext, int N,
    int relu_in) {
  const int lane = threadIdx.x & 63;
  const int wv = threadIdx.x >> 6;
  const int c0 = __builtin_amdgcn_readfirstlane(wv << 4);
  const int n = blockIdx.x * 64 + lane;

  float acc[16];
#pragma unroll
  for (int jj = 0; jj < 16; ++jj) acc[jj] = brel[c0 + jj];

  float in[DD];
#pragma unroll 1
  for (int m = 0; m < 5; ++m) {
    const float* __restrict__ W =
        (m < 4) ? (Wrel + (size_t)m * DD * DD) : Wloop;
    if (n < N) {
      const float4* p = (m < 4)
                            ? (const float4*)(aggr + ((size_t)n << 8) + (m << 6))
                            : (const float4*)(hin + ((size_t)n << 6));
#pragma unroll
      for (int t = 0; t < DD / 4; ++t) {
        float4 v = p[t];
        if (m == 4 && relu_in) {
          v.x = fmaxf(v.x, 0.f); v.y = fmaxf(v.y, 0.f);
          v.z = fmaxf(v.z, 0.f); v.w = fmaxf(v.w, 0.f);
        }
        in[4 * t + 0] = v.x; in[4 * t + 1] = v.y;
        in[4 * t + 2] = v.z; in[4 * t + 3] = v.w;
      }
    } else {
#pragma unroll
      for (int t = 0; t < DD; ++t) in[t] = 0.f;
    }
#pragma unroll
    for (int k = 0; k < DD; ++k) {
      const float hk = in[k];
#pragma unroll
      for (int jj = 0; jj < 16; ++jj)
        acc[jj] = fmaf(hk, W[k * DD + c0 + jj], acc[jj]);
    }
  }
  if (n < N) {
    float* o = hnext + ((size_t)n << 6) + c0;
#pragma unroll
    for (int jj = 0; jj < 16; jj += 4)
      *(float4*)(o + jj) =
          make_float4(acc[jj], acc[jj + 1], acc[jj + 2], acc[jj + 3]);
  }
}

// ================= z = relu(h) @ Wg =================
__global__ __launch_bounds__(256) void gemm_relu64(const float* __restrict__ hin,
                                                   const float* __restrict__ W,
                                                   float* __restrict__ out,
                                                   int N) {
  const int lane = threadIdx.x & 63;
  const int wv = threadIdx.x >> 6;
  const int c0 = __builtin_amdgcn_readfirstlane(wv << 4);
  const int n = blockIdx.x * 64 + lane;

  float h[DD];
  if (n < N) {
    const float4* hp = (const float4*)(hin + (size_t)n * DD);
#pragma unroll
    for (int t = 0; t < DD / 4; ++t) {
      float4 v = hp[t];
      v.x = fmaxf(v.x, 0.f); v.y = fmaxf(v.y, 0.f);
      v.z = fmaxf(v.z, 0.f); v.w = fmaxf(v.w, 0.f);
      h[4 * t + 0] = v.x; h[4 * t + 1] = v.y;
      h[4 * t + 2] = v.z; h[4 * t + 3] = v.w;
    }
  } else {
#pragma unroll
    for (int t = 0; t < DD; ++t) h[t] = 0.f;
  }
  float acc[16];
#pragma unroll
  for (int j = 0; j < 16; ++j) acc[j] = 0.f;
#pragma unroll
  for (int k = 0; k < DD; ++k) {
    const float hk = h[k];
#pragma unroll
    for (int j = 0; j < 16; ++j)
      acc[j] = fmaf(hk, W[k * DD + c0 + j], acc[j]);
  }
  if (n < N) {
    float* o = out + ((size_t)n << 6) + c0;
#pragma unroll
    for (int j = 0; j < 16; j += 4)
      *(float4*)(o + j) =
          make_float4(acc[j], acc[j + 1], acc[j + 2], acc[j + 3]);
  }
}

// ================= GAT: el/er per node =================
__global__ __launch_bounds__(256) void el_er_k(
    const float* __restrict__ z, const float* __restrict__ al,
    const float* __restrict__ ar, float* __restrict__ el,
    float* __restrict__ er, int N) {
  int n = blockIdx.x * 4 + (threadIdx.x >> 6);
  int lane = threadIdx.x & 63;
  if (n >= N) return;
  float v = z[(size_t)n * DD + lane];
  float pl = v * al[lane];
  float pr = v * ar[lane];
#pragma unroll
  for (int off = 32; off > 0; off >>= 1) {
    pl += __shfl_down(pl, off);
    pr += __shfl_down(pr, off);
  }
  if (lane == 0) {
    el[n] = pl;
    er[n] = pr;
  }
}

// ================= fused GAT aggregation (per destination node) =================
__global__ __launch_bounds__(256) void gat_fused(
    const float* __restrict__ z, const float* __restrict__ el,
    const float* __restrict__ er, const int* __restrict__ rowptr,
    const int* __restrict__ srcet, float* __restrict__ hg, int N) {
  const int n = blockIdx.x * 4 + (threadIdx.x >> 6);
  const int lane = threadIdx.x & 63;
  const int g = lane >> 4;
  const int t = lane & 15;
  if (n >= N) return;
  const int beg = rowptr[n], end = rowptr[n + 1];
  const float ern = er[n];

  // phase A: online (m, den) with 64 edges in flight
  float m = -1e30f, den = 0.f;
  for (int j = beg + lane; j < end; j += 64) {
    const int s = srcet[j] >> 2;
    float x = el[s] + ern;
    x = (x > 0.f) ? x : 0.2f * x;
    if (x > m) {
      den *= __expf(m - x);
      m = x;
    }
    den += __expf(x - m);
  }
#pragma unroll
  for (int off = 1; off < 64; off <<= 1) {
    float mo = __shfl_xor(m, off);
    float dn = __shfl_xor(den, off);
    float M = fmaxf(m, mo);
    den = den * __expf(m - M) + dn * __expf(mo - M);
    m = M;
  }

  // phase B: weighted gather, 4 edges in flight
  float4 num = make_float4(0.f, 0.f, 0.f, 0.f);
  for (int j = beg + g; j < end; j += 4) {
    const int se = srcet[j];
    const int s = se >> 2;
    float x = el[s] + ern;
    x = (x > 0.f) ? x : 0.2f * x;
    const float w = __expf(x - m);
    float4 v = *(const float4*)(z + ((size_t)s << 6) + (t << 2));
    num.x = fmaf(w, v.x, num.x);
    num.y = fmaf(w, v.y, num.y);
    num.z = fmaf(w, v.z, num.z);
    num.w = fmaf(w, v.w, num.w);
  }
#pragma unroll
  for (int off = 16; off <= 32; off <<= 1) {
    num.x += __shfl_xor(num.x, off);
    num.y += __shfl_xor(num.y, off);
    num.z += __shfl_xor(num.z, off);
    num.w += __shfl_xor(num.w, off);
  }
  if (g == 0) {
    const float inv = 1.f / fmaxf(den, 1e-9f);
    float4 o = make_float4(num.x * inv, num.y * inv, num.z * inv, num.w * inv);
    *(float4*)(hg + ((size_t)n << 6) + (t << 2)) = o;
  }
}

// ================= pooled head, two-level (LDS per-gid table, sorted gids) =========
__global__ __launch_bounds__(256) void pool_head2(
    const float* __restrict__ hg, const float* __restrict__ Wd,
    const int* __restrict__ gids, float* __restrict__ out, int N, int B) {
  __shared__ float acc[1024];
  for (int i = threadIdx.x; i < B; i += 256) acc[i] = 0.f;
  __syncthreads();

  const int wv = threadIdx.x >> 6;
  const int lane = threadIdx.x & 63;
  const int sub = lane & 3;
  const int idx = lane >> 2;

  const float4 w0 = *(const float4*)(Wd + (sub << 4) + 0);
  const float4 w1 = *(const float4*)(Wd + (sub << 4) + 4);
  const float4 w2 = *(const float4*)(Wd + (sub << 4) + 8);
  const float4 w3 = *(const float4*)(Wd + (sub << 4) + 12);

  const int base0 = blockIdx.x * POOL_NPB;
#pragma unroll 1
  for (int it = 0; it < POOL_NPB / 64; ++it) {
    const int n = base0 + it * 64 + wv * 16 + idx;
    if (n < N) {
      const float* p = hg + ((size_t)n << 6) + (sub << 4);
      const float4 v0 = *(const float4*)(p + 0);
      const float4 v1 = *(const float4*)(p + 4);
      const float4 v2 = *(const float4*)(p + 8);
      const float4 v3 = *(const float4*)(p + 12);
      float s = v0.x * w0.x + v0.y * w0.y + v0.z * w0.z + v0.w * w0.w;
      s = fmaf(v1.x, w1.x, s); s = fmaf(v1.y, w1.y, s);
      s = fmaf(v1.z, w1.z, s); s = fmaf(v1.w, w1.w, s);
      s = fmaf(v2.x, w2.x, s); s = fmaf(v2.y, w2.y, s);
      s = fmaf(v2.z, w2.z, s); s = fmaf(v2.w, w2.w, s);
      s = fmaf(v3.x, w3.x, s); s = fmaf(v3.y, w3.y, s);
      s = fmaf(v3.z, w3.z, s); s = fmaf(v3.w, w3.w, s);
      s += __shfl_xor(s, 1);
      s += __shfl_xor(s, 2);
      if (sub == 0) atomicAdd(&acc[gids[n]], s);
    }
  }
  __syncthreads();
  for (int i = threadIdx.x; i < B; i += 256) {
    const float v = acc[i];
    if (v != 0.f) unsafeAtomicAdd(out + i, v);
  }
}

__global__ void init_out_k(float* out, const float* bd, int n) {
  int i = blockIdx.x * blockDim.x + threadIdx.x;
  if (i < n) out[i] = bd[0];
}

// ================= launch =================
extern "C" void kernel_launch(void* const* d_in, const int* in_sizes, int n_in,
                              void* d_out, int out_size, void* d_ws,
                              size_t ws_size, hipStream_t stream) {
  const float* h0 = (const float*)d_in[0];
  const float* Wrel = (const float*)d_in[1];
  const float* Wloop = (const float*)d_in[2];
  const float* brel = (const float*)d_in[3];
  const float* Wg = (const float*)d_in[4];
  const float* al = (const float*)d_in[5];
  const float* ar = (const float*)d_in[6];
  const float* Wd = (const float*)d_in[7];
  const float* bd = (const float*)d_in[8];
  const int* src = (const int*)d_in[9];
  const int* dst = (const int*)d_in[10];
  const int* et = (const int*)d_in[11];
  const int* gids = (const int*)d_in[12];

  const int N = in_sizes[0] / DD;
  const int E = in_sizes[9];
  const int L = in_sizes[2] / (DD * DD);
  float* out = (float*)d_out;

  // ---- workspace layout ----
  float* wsf = (float*)d_ws;
  float* hA = wsf;                          // N*64
  float* hB = hA + (size_t)N * DD;          // N*64
  float* aggr = hB + (size_t)N * DD;        // N*256
  int* rowptr = (int*)(aggr + (size_t)N * 4 * DD);  // N+1
  int* cursor = rowptr + N + 1;             // N
  int* deg = cursor + N;                    // N
  int* srcet = deg + N;                     // E
  float* el = (float*)(srcet + E);          // N
  float* er = el + N;                       // N
  int* partials = (int*)(er + N);           // up to 256
  float* hg = aggr;                         // overlay: aggr dead after last dense

  dim3 b256(256);
  const int grid_dense = (N + 63) / 64;
  const int grid_e = (E + 255) / 256;
  const int grid_n4 = (N + 3) / 4;
  const int nb = (N + 255) / 256;  // scan blocks (must be <= 256)

  hipLaunchKernelGGL(init_out_k, dim3((out_size + 255) / 256), b256, 0, stream,
                     out, bd, out_size);

  // ---- CSR build ----
  hipMemsetAsync(deg, 0, (size_t)N * 4, stream);
  hipLaunchKernelGGL(k_deg, dim3(grid_e), b256, 0, stream, dst, deg, E);
  hipLaunchKernelGGL(k_scan1, dim3(nb), b256, 0, stream, deg, partials, N);
  hipLaunchKernelGGL(k_scan2, dim3(1), b256, 0, stream, partials, nb);
  hipLaunchKernelGGL(k_scan3, dim3(nb), b256, 0, stream, deg, partials, rowptr,
                     cursor, N, E);
  hipLaunchKernelGGL(k_fill, dim3(grid_e), b256, 0, stream, src, dst, et,
                     cursor, srcet, E);

  // ---- RGCN layers ----
  const float* cur = h0;
  float* nxt = hA;
  for (int l = 0; l < L; ++l) {
    hipLaunchKernelGGL(gather_rel, dim3(grid_n4), b256, 0, stream, cur, rowptr,
                       srcet, aggr, N, l > 0 ? 1 : 0);
    hipLaunchKernelGGL(rgcn_dense, dim3(grid_dense), b256, 0, stream, aggr, cur,
                       Wrel + (size_t)l * 4 * DD * DD,
                       Wloop + (size_t)l * DD * DD, brel + (size_t)l * DD, nxt,
                       N, l > 0 ? 1 : 0);
    cur = nxt;
    nxt = (cur == hA) ? hB : hA;
  }

  // ---- GAT ----
  float* zb = nxt;
  hipLaunchKernelGGL(gemm_relu64, dim3(grid_dense), b256, 0, stream, cur, Wg,
                     zb, N);
  hipLaunchKernelGGL(el_er_k, dim3(grid_n4), b256, 0, stream, zb, al, ar, el,
                     er, N);
  hipLaunchKernelGGL(gat_fused, dim3(grid_n4), b256, 0, stream, zb, el, er,
                     rowptr, srcet, hg, N);

  const int grid_pool = (N + POOL_NPB - 1) / POOL_NPB;
  hipLaunchKernelGGL(pool_head2, dim3(grid_pool), b256, 0, stream, hg, Wd, gids,
                     out, N, out_size);
}